// Round 8
// baseline (569.676 us; speedup 1.0000x reference)
//
#include <hip/hip_runtime.h>

#define BB 8
#define MM 4096
#define EE 2048
#define DD 128

typedef _Float16 f16x8 __attribute__((ext_vector_type(8)));
typedef float    f32x4 __attribute__((ext_vector_type(4)));

// ---------------------------------------------------------------------------
// transpose_to16: src [R][C] fp32 -> dst [C][R] f16, batch = blockIdx.y.
// ---------------------------------------------------------------------------
__global__ __launch_bounds__(256) void transpose_to16(const float* __restrict__ src,
                                                      _Float16* __restrict__ dst,
                                                      int R, int C)
{
    __shared__ alignas(16) float tile[64 * 67];
    const int tilesC = C >> 6;
    const int r0 = (blockIdx.x / tilesC) << 6;
    const int c0 = (blockIdx.x % tilesC) << 6;
    const float* s = src + (size_t)blockIdx.y * R * C;
    _Float16*   d = dst + (size_t)blockIdx.y * R * C;
    const int t = threadIdx.x;
    #pragma unroll
    for (int i = 0; i < 4; i++){
        int idx = t + 256 * i;
        int r = idx >> 4, c4 = idx & 15;
        float4 v = *(const float4*)(s + (size_t)(r0 + r) * C + c0 + c4 * 4);
        tile[(c4 * 4 + 0) * 67 + r] = v.x;
        tile[(c4 * 4 + 1) * 67 + r] = v.y;
        tile[(c4 * 4 + 2) * 67 + r] = v.z;
        tile[(c4 * 4 + 3) * 67 + r] = v.w;
    }
    __syncthreads();
    #pragma unroll
    for (int i = 0; i < 2; i++){
        int idx = t + 256 * i;
        int row = idx >> 3, rb = idx & 7;
        f16x8 h;
        #pragma unroll
        for (int j = 0; j < 8; j++) h[j] = (_Float16)tile[row * 67 + rb * 8 + j];
        *(f16x8*)(d + (size_t)(c0 + row) * R + r0 + rb * 8) = h;
    }
}

// ---------------------------------------------------------------------------
// fused_gemm1 (wave-specialized): one inc pass produces bitsX + split-K agg.
//   waves 0-1 (pack): stage 64 inc rows x 64 e in regs (val[64] -> loads stay
//     outstanding until stage), double-ballot -> bitsX word + LDS bitsT.
//   waves 2-3 (dense): stage featT chunk (rd[8]).
//   all waves: MFMA 32e x 128d from LDS bits + LDS dense.
// Tile 128 e x 128 d, BK = 64 m, split-K x2 (2048 m each), 32 chunks.
// Grid (EE/128=16, BB, 2) = 256 blocks = 1/CU.
// Register budget: pack path ~150 VGPR, dense path ~110 -> no spill.
// ---------------------------------------------------------------------------
__global__ __launch_bounds__(256, 1) void fused_gemm1(const float* __restrict__ inc,
                                                      const _Float16* __restrict__ featT,
                                                      unsigned long long* __restrict__ bitsX,
                                                      float* __restrict__ p)
{
    __shared__ alignas(16) char smem[34816];   // [0,32K) dense dbuf; [32K,34K) bits dbuf

    const int x = blockIdx.x;                  // e-block (128 e)
    const int b = blockIdx.y;
    const int z = blockIdx.z;                  // K-slice (2048 m)
    const int t = threadIdx.x, lane = t & 63, w = t >> 6;
    const int fr = lane & 15, q = lane >> 4, q8 = q * 8;

    const int e0 = x * 128;
    const _Float16* dp = featT + (size_t)b * 128 * MM;
    const float* ip = inc + (size_t)b * MM * EE + e0 + (w & 1) * 64 + lane; // pack waves
    unsigned long long* bxp = bitsX + ((size_t)b * 32 + (x * 2 + (w & 1))) * MM;

    f32x4 acc[2][8] = {};                      // 32 e-rows x 128 d per wave
    float val[64];                             // pack waves only
    uint4 rd[8];                               // dense waves only

    auto loadg = [&](int k0){
        if (w < 2){
            const float* rp = ip + (size_t)k0 * EE;
            #pragma unroll
            for (int j = 0; j < 64; j++) val[j] = rp[(size_t)j * EE];
        } else {
            #pragma unroll
            for (int i = 0; i < 8; i++){
                int vid = (w - 2) * 64 + lane + 128 * i;   // 1024 f16x8 vectors
                int dd = vid >> 3, kb = vid & 7;
                rd[i] = *(const uint4*)(dp + (size_t)dd * MM + k0 + kb * 8);
            }
        }
    };
    auto stage = [&](int buf, int k0){
        if (w < 2){
            // pack: lane j keeps e-bit word (this wave's 64-e half) of row k0+j
            unsigned long long wbits = 0;
            #pragma unroll
            for (int j = 0; j < 64; j++){
                unsigned long long bal = __ballot(val[j] != 0.0f);
                wbits = (lane == j) ? bal : wbits;
            }
            bxp[k0 + lane] = wbits;            // contiguous 512 B per wave
            // transpose: lane ei keeps m-bit word of e-col (local) w*64+ei
            unsigned long long wT = 0;
            #pragma unroll
            for (int ei = 0; ei < 64; ei++){
                unsigned long long bal = __ballot((wbits >> ei) & 1ull);
                wT = (lane == ei) ? bal : wT;
            }
            unsigned long long* lBits = (unsigned long long*)(smem + 32768 + buf * 1024);
            lBits[(w & 1) * 64 + lane] = wT;
        } else {
            _Float16* lD = (_Float16*)(smem + buf * 16384);
            #pragma unroll
            for (int i = 0; i < 8; i++){
                int vid = (w - 2) * 64 + lane + 128 * i;
                int dd = vid >> 3, kb = vid & 7;
                *(uint4*)&lD[dd * 64 + ((kb ^ (dd & 7)) * 8)] = rd[i];
            }
        }
    };
    auto compute = [&](int buf){
        const _Float16* lD = (const _Float16*)(smem + buf * 16384);
        const uint2* lB = (const uint2*)(smem + 32768 + buf * 1024);
        uint2 bw[2];
        #pragma unroll
        for (int r = 0; r < 2; r++)
            bw[r] = lB[w * 32 + r * 16 + fr];  // local e-row, q-broadcast
        #pragma unroll
        for (int h = 0; h < 2; h++){
            f16x8 af[2];
            #pragma unroll
            for (int r = 0; r < 2; r++){
                unsigned word = h ? bw[r].y : bw[r].x;
                unsigned byte = (word >> q8) & 0xFFu;
                #pragma unroll
                for (int j = 0; j < 8; j++)
                    af[r][j] = ((byte >> j) & 1u) ? (_Float16)1.0f : (_Float16)0.0f;
            }
            #pragma unroll
            for (int c = 0; c < 8; c++){
                int drow = c * 16 + fr;
                f16x8 bf = *(const f16x8*)&lD[drow * 64 + (((h * 4 + q) ^ (drow & 7)) * 8)];
                #pragma unroll
                for (int r = 0; r < 2; r++)
                    acc[r][c] = __builtin_amdgcn_mfma_f32_16x16x32_f16(af[r], bf, acc[r][c], 0, 0, 0);
            }
        }
    };

    const int kbase = z * 2048;
    loadg(kbase); stage(0, kbase); __syncthreads();
    for (int c = 0; c < 32; c++){
        if (c + 1 < 32) loadg(kbase + (c + 1) * 64);   // loads only, no waits
        compute(c & 1);
        if (c + 1 < 32) stage((c + 1) & 1, kbase + (c + 1) * 64);
        __syncthreads();
    }

    // Epilogue: 2 phases x 64 e-rows through LDS, full-line float4 stores.
    float* sT = (float*)smem;                  // [64][132] = 33792 B
    float* op = p + (size_t)z * 2097152 + ((size_t)b * EE + e0) * 128;
    for (int ph = 0; ph < 2; ph++){
        __syncthreads();
        if ((w >> 1) == ph){
            int rbase = (w & 1) * 32;
            #pragma unroll
            for (int r = 0; r < 2; r++)
                #pragma unroll
                for (int c = 0; c < 8; c++)
                    #pragma unroll
                    for (int reg = 0; reg < 4; reg++)
                        sT[(rbase + r * 16 + q * 4 + reg) * 132 + c * 16 + fr] = acc[r][c][reg];
        }
        __syncthreads();
        #pragma unroll
        for (int i = 0; i < 8; i++){
            int idx = t + 256 * i;
            int lrow = idx >> 5, c4 = idx & 31;
            float4 v = *(const float4*)&sT[lrow * 132 + c4 * 4];
            *(float4*)(op + (size_t)(ph * 64 + lrow) * 128 + c4 * 4) = v;
        }
    }
}

// ---------------------------------------------------------------------------
// bitgemm2_fused: Q[m][j] = sum_e bit(m,e)*PT[j][e]; node[m][n] = sum_j
// Q[m][j]*Wc16[n][j]. bitsX layout -> contiguous per-chunk bit-word loads.
// ---------------------------------------------------------------------------
__global__ __launch_bounds__(256) void bitgemm2_fused(const unsigned long long* __restrict__ bitsX,
                                                      const _Float16* __restrict__ PT,
                                                      const _Float16* __restrict__ Wc16,
                                                      float* __restrict__ node)
{
    __shared__ alignas(16) char smem[66560];   // [0,32K) dense dbuf; [32K,33K) bits; [33K,65K) Wc
    const int b = blockIdx.y;
    const int m0 = blockIdx.x * 64;
    const unsigned long long* bxp = bitsX + (size_t)b * 32 * MM;
    const _Float16* dp = PT + (size_t)b * 128 * EE;
    float* op = node + ((size_t)b * MM + m0) * 128;

    const int t = threadIdx.x, lane = t & 63, w = t >> 6;
    const int fr = lane & 15, q = lane >> 4, q8 = q * 8;

    _Float16* lWc = (_Float16*)(smem + 33792);
    #pragma unroll
    for (int i = 0; i < 8; i++){
        int idx = t + 256 * i;
        int n = idx >> 4, kb = idx & 15;
        *(uint4*)&lWc[n * 128 + ((kb ^ (n & 7)) * 8)] =
            *(const uint4*)(Wc16 + (size_t)n * 128 + kb * 8);
    }

    f32x4 acc[8] = {};
    uint4 rd[4];
    unsigned long long rb;

    auto loadg = [&](int kg){
        #pragma unroll
        for (int i = 0; i < 4; i++){
            int idx = t + 256 * i;
            int dd = idx >> 3, kb = idx & 7;
            rd[i] = *(const uint4*)(dp + (size_t)dd * EE + kg + kb * 8);
        }
        if (t < 64) rb = bxp[(size_t)(kg >> 6) * MM + m0 + t];   // contiguous
    };
    auto stage = [&](int buf){
        _Float16* lD = (_Float16*)(smem + buf * 16384);
        unsigned long long* lB = (unsigned long long*)(smem + 32768 + buf * 512);
        #pragma unroll
        for (int i = 0; i < 4; i++){
            int idx = t + 256 * i;
            int dd = idx >> 3, kb = idx & 7;
            *(uint4*)&lD[dd * 64 + ((kb ^ (dd & 7)) * 8)] = rd[i];
        }
        if (t < 64) lB[t] = rb;
    };
    auto compute = [&](int buf){
        const _Float16* lD = (const _Float16*)(smem + buf * 16384);
        const uint2* lB = (const uint2*)(smem + 32768 + buf * 512);
        uint2 bw = lB[w * 16 + fr];
        #pragma unroll
        for (int h = 0; h < 2; h++){
            unsigned word = h ? bw.y : bw.x;
            unsigned byte = (word >> q8) & 0xFFu;
            f16x8 af;
            #pragma unroll
            for (int j = 0; j < 8; j++)
                af[j] = ((byte >> j) & 1u) ? (_Float16)1.0f : (_Float16)0.0f;
            #pragma unroll
            for (int c = 0; c < 8; c++){
                int drow = c * 16 + fr;
                f16x8 bf = *(const f16x8*)&lD[drow * 64 + (((h * 4 + q) ^ (drow & 7)) * 8)];
                acc[c] = __builtin_amdgcn_mfma_f32_16x16x32_f16(af, bf, acc[c], 0, 0, 0);
            }
        }
    };

    loadg(0); stage(0); __syncthreads();
    for (int c = 0; c < 32; c++){
        if (c + 1 < 32) loadg((c + 1) * 64);
        compute(c & 1);
        if (c + 1 < 32) stage((c + 1) & 1);
        __syncthreads();
    }

    // Phase 2: Q (f16, per-wave-private rows) @ Wc^T via MFMA.
    _Float16* sQ = (_Float16*)smem;
    #pragma unroll
    for (int c = 0; c < 8; c++){
        #pragma unroll
        for (int reg = 0; reg < 4; reg++){
            int row = w * 16 + q * 4 + reg;
            int col = c * 16 + fr;
            sQ[row * 128 + (((col >> 3) ^ (row & 7)) * 8) + (col & 7)] = (_Float16)acc[c][reg];
        }
    }
    f32x4 acc2[8] = {};
    #pragma unroll
    for (int kk = 0; kk < 4; kk++){
        int arow = w * 16 + fr;
        f16x8 a2 = *(const f16x8*)&sQ[arow * 128 + (((kk * 4 + q) ^ (arow & 7)) * 8)];
        #pragma unroll
        for (int c = 0; c < 8; c++){
            int n = c * 16 + fr;
            f16x8 b2 = *(const f16x8*)&lWc[n * 128 + (((kk * 4 + q) ^ (n & 7)) * 8)];
            acc2[c] = __builtin_amdgcn_mfma_f32_16x16x32_f16(a2, b2, acc2[c], 0, 0, 0);
        }
    }
    __syncthreads();
    float* sD = (float*)smem;
    #pragma unroll
    for (int c = 0; c < 8; c++)
        #pragma unroll
        for (int reg = 0; reg < 4; reg++)
            sD[(w * 16 + q * 4 + reg) * 132 + c * 16 + fr] = acc2[c][reg];
    __syncthreads();
    #pragma unroll
    for (int i = 0; i < 8; i++){
        int idx = t + 256 * i;
        int lrow = idx >> 5, c4 = idx & 31;
        float4 v = *(const float4*)&sD[lrow * 132 + c4 * 4];
        *(float4*)(op + (size_t)lrow * 128 + c4 * 4) = v;
    }
}

// ---------------------------------------------------------------------------
// rowmm_sum2: A = p0+p1; A -> aggOut (aliases p0, safe) and C = A@W^T -> C.
// ---------------------------------------------------------------------------
__global__ __launch_bounds__(256) void rowmm_sum2(const float* __restrict__ p,
                                                  const float* __restrict__ W,
                                                  float* aggOut,
                                                  float* __restrict__ C)
{
    __shared__ alignas(16) float lA[32][132];
    __shared__ alignas(16) float lW[64][140];
    const int t = threadIdx.x;
    const int row0 = blockIdx.x * 32;
    const float4* P4 = (const float4*)p;
    const float4* W4 = (const float4*)W;
    float4* A4 = (float4*)aggOut;
    const size_t SS = 2097152 / 4;

    #pragma unroll
    for (int i = 0; i < 4; i++){
        int idx = t + 256 * i;
        int r = idx >> 5, k4 = idx & 31;
        size_t gi = (size_t)(row0 + r) * 32 + k4;
        float4 a = P4[gi], b = P4[gi + SS];
        float4 s = make_float4(a.x + b.x, a.y + b.y, a.z + b.z, a.w + b.w);
        *(float4*)&lA[r][k4 * 4] = s;
        A4[gi] = s;
    }
    const int qq = t >> 5, cc = t & 31;

    #pragma unroll
    for (int ph = 0; ph < 2; ph++){
        __syncthreads();
        #pragma unroll
        for (int i = 0; i < 8; i++){
            int idx = t + 256 * i;
            int c = idx >> 5, k4 = idx & 31;
            *(float4*)&lW[c][k4 * 4] = W4[(size_t)(ph * 64 + c) * 32 + k4];
        }
        __syncthreads();
        float s[4][2] = {};
        for (int k4 = 0; k4 < 32; k4++){
            float4 w0 = *(const float4*)&lW[cc][k4 * 4];
            float4 w1 = *(const float4*)&lW[cc + 32][k4 * 4];
            #pragma unroll
            for (int j = 0; j < 4; j++){
                float4 a = *(const float4*)&lA[qq + 8 * j][k4 * 4];
                s[j][0] += a.x * w0.x + a.y * w0.y + a.z * w0.z + a.w * w0.w;
                s[j][1] += a.x * w1.x + a.y * w1.y + a.z * w1.z + a.w * w1.w;
            }
        }
        #pragma unroll
        for (int j = 0; j < 4; j++){
            size_t ro = (size_t)(row0 + qq + 8 * j) * DD + ph * 64;
            C[ro + cc]      = s[j][0];
            C[ro + cc + 32] = s[j][1];
        }
    }
}

// ---------------------------------------------------------------------------
// rowmm: C[n,:] = A[n,:] @ W^T, fp32.
// ---------------------------------------------------------------------------
__global__ __launch_bounds__(256) void rowmm(const float* A,
                                             const float* __restrict__ W,
                                             float* C)
{
    __shared__ alignas(16) float lA[32][132];
    __shared__ alignas(16) float lW[64][140];
    const int t = threadIdx.x;
    const int row0 = blockIdx.x * 32;
    const float4* A4 = (const float4*)A;
    const float4* W4 = (const float4*)W;

    #pragma unroll
    for (int i = 0; i < 4; i++){
        int idx = t + 256 * i;
        int r = idx >> 5, k4 = idx & 31;
        *(float4*)&lA[r][k4 * 4] = A4[(size_t)(row0 + r) * 32 + k4];
    }
    const int qq = t >> 5, cc = t & 31;

    #pragma unroll
    for (int ph = 0; ph < 2; ph++){
        __syncthreads();
        #pragma unroll
        for (int i = 0; i < 8; i++){
            int idx = t + 256 * i;
            int c = idx >> 5, k4 = idx & 31;
            *(float4*)&lW[c][k4 * 4] = W4[(size_t)(ph * 64 + c) * 32 + k4];
        }
        __syncthreads();
        float s[4][2] = {};
        for (int k4 = 0; k4 < 32; k4++){
            float4 w0 = *(const float4*)&lW[cc][k4 * 4];
            float4 w1 = *(const float4*)&lW[cc + 32][k4 * 4];
            #pragma unroll
            for (int j = 0; j < 4; j++){
                float4 a = *(const float4*)&lA[qq + 8 * j][k4 * 4];
                s[j][0] += a.x * w0.x + a.y * w0.y + a.z * w0.z + a.w * w0.w;
                s[j][1] += a.x * w1.x + a.y * w1.y + a.z * w1.z + a.w * w1.w;
            }
        }
        #pragma unroll
        for (int j = 0; j < 4; j++){
            size_t ro = (size_t)(row0 + qq + 8 * j) * DD + ph * 64;
            C[ro + cc]      = s[j][0];
            C[ro + cc + 32] = s[j][1];
        }
    }
}

// ---------------------------------------------------------------------------
// wc_mm16: Wc16 = f16(eWp @ vWp)  (128x128x128)
// ---------------------------------------------------------------------------
__global__ __launch_bounds__(256) void wc_mm16(const float* __restrict__ eWp,
                                               const float* __restrict__ vWp,
                                               _Float16* __restrict__ Wc16)
{
    int i = blockIdx.x * 2 + (threadIdx.x >> 7);
    int j = threadIdx.x & 127;
    float acc = 0.f;
    for (int k = 0; k < 128; k++)
        acc += eWp[i * 128 + k] * vWp[k * 128 + j];
    Wc16[i * 128 + j] = (_Float16)acc;
}

// ---------------------------------------------------------------------------
// Online softmax over e (two passes, coalesced).
// ---------------------------------------------------------------------------
__global__ __launch_bounds__(256) void sm_part(const float* __restrict__ eatt,
                                               float* __restrict__ part)
{
    const int b = blockIdx.x, slab = blockIdx.y;
    const int t = threadIdx.x;
    const int dl = t & 127, eh = t >> 7;
    const size_t base = (size_t)b * EE * DD + dl;
    const int e0 = slab * 256;
    float m = -1e30f;
    for (int s = 0; s < 128; s++)
        m = fmaxf(m, eatt[base + (size_t)(e0 + eh + 2 * s) * DD]);
    float l = 0.f;
    for (int s = 0; s < 128; s++)
        l += __expf(eatt[base + (size_t)(e0 + eh + 2 * s) * DD] - m);
    __shared__ float red[2][128][2];
    red[eh][dl][0] = m; red[eh][dl][1] = l;
    __syncthreads();
    if (t < 128){
        float m0 = red[0][t][0], l0 = red[0][t][1];
        float m1 = red[1][t][0], l1 = red[1][t][1];
        float M = fmaxf(m0, m1);
        float L = l0 * __expf(m0 - M) + l1 * __expf(m1 - M);
        float* pp = part + ((size_t)(b * 8 + slab) * DD + t) * 2;
        pp[0] = M; pp[1] = L;
    }
}

__global__ __launch_bounds__(256) void sm_apply(float* __restrict__ eatt,
                                                const float* __restrict__ agg,
                                                const float* __restrict__ part)
{
    const int b = blockIdx.x, sl = blockIdx.y;
    const int t = threadIdx.x;
    __shared__ float mv[128], iv[128];
    if (t < 128){
        float mbuf[8], lbuf[8];
        float M = -1e30f;
        #pragma unroll
        for (int s = 0; s < 8; s++){
            const float* pp = part + ((size_t)(b * 8 + s) * DD + t) * 2;
            mbuf[s] = pp[0]; lbuf[s] = pp[1];
            M = fmaxf(M, mbuf[s]);
        }
        float L = 0.f;
        #pragma unroll
        for (int s = 0; s < 8; s++) L += lbuf[s] * __expf(mbuf[s] - M);
        mv[t] = M; iv[t] = 1.f / L;
    }
    __syncthreads();
    const int dl = t & 127, eh = t >> 7;
    const size_t base = (size_t)b * EE * DD + dl;
    const int e0 = sl * 128;
    for (int s = 0; s < 64; s++){
        size_t ix = base + (size_t)(e0 + eh + 2 * s) * DD;
        eatt[ix] = agg[ix] * __expf(eatt[ix] - mv[dl]) * iv[dl];
    }
}

// ---------------------------------------------------------------------------
// Pipeline (layer recursion = fixed point; ec_Wa dead):
//  1. featT = T(feat) f16 ; Wc16 = f16(eWp@vWp)
//  2. fused_gemm1 (wave-specialized): ONE inc pass -> p0,p1 + bitsX
//  3. agg = p0+p1 ; eatt = agg@vWa^T (fused)
//  4. softmax -> P (in-place)
//  5. edge = P@vWp^T (OUT2); PT = T(P) f16
//  6. node = (inc@P)@Wc^T fused bitgemm2 (OUT1)
// ws: [0,8M)=bitsX; [8,24M)=p0,p1 (agg over p0, PT over p1); [24M)=Wc16.
// d_out: node[0,8M)=featT; node[8,16M)=eatt/P; edge=part->edge.
// ---------------------------------------------------------------------------
extern "C" void kernel_launch(void* const* d_in, const int* in_sizes, int n_in,
                              void* d_out, int out_size, void* d_ws, size_t ws_size,
                              hipStream_t stream)
{
    const float* feat = (const float*)d_in[0];
    const float* inc  = (const float*)d_in[1];
    const float* vWa  = (const float*)d_in[2];
    const float* vWp  = (const float*)d_in[3];
    const float* eWp  = (const float*)d_in[6];

    float* node_out = (float*)d_out;
    float* edge_out = node_out + (size_t)BB * MM * DD;

    char* w = (char*)d_ws;
    unsigned long long* bitsX = (unsigned long long*)w;        // [0,8M)
    float* pk  = (float*)(w + ((size_t)8 << 20));              // p0,p1 (8 MB each)
    float* agg = pk;                                           // over p0
    _Float16* PT = (_Float16*)(w + ((size_t)16 << 20));        // over p1 (dead after sum2)
    _Float16* Wc16 = (_Float16*)(w + ((size_t)24 << 20));

    _Float16* featT = (_Float16*)node_out;                     // node[0,8M)
    float* eattP = node_out + 2097152;                         // node[8,16M)
    float* part  = edge_out;                                   // dead before edge

    dim3 blk(256);

    // 1. featT + Wc16
    transpose_to16<<<dim3((MM / 64) * (DD / 64), BB), blk, 0, stream>>>(feat, featT, MM, DD);
    wc_mm16<<<dim3(64), blk, 0, stream>>>(eWp, vWp, Wc16);
    // 2. one inc pass: p partials + bitsX
    fused_gemm1<<<dim3(EE / 128, BB, 2), blk, 0, stream>>>(inc, featT, bitsX, pk);
    // 3. agg = p0+p1 ; eatt = agg @ vWa^T
    rowmm_sum2<<<dim3(BB * EE / 32), blk, 0, stream>>>(pk, vWa, agg, eattP);
    // 4. P = agg * softmax_e(eatt)
    sm_part <<<dim3(BB, 8),  blk, 0, stream>>>(eattP, part);
    sm_apply<<<dim3(BB, 16), blk, 0, stream>>>(eattP, agg, part);
    // 5. edge = P @ vWp^T (OUT2); PT = f16(P^T)
    rowmm<<<dim3(BB * EE / 32), blk, 0, stream>>>(eattP, vWp, edge_out);
    transpose_to16<<<dim3((EE / 64) * (DD / 64), BB), blk, 0, stream>>>(eattP, PT, EE, DD);
    // 6. node = (inc@P) @ Wc^T fused (OUT1)
    bitgemm2_fused<<<dim3(MM / 64, BB), blk, 0, stream>>>(bitsX, PT, Wc16, node_out);
}